// Round 8
// baseline (376.613 us; speedup 1.0000x reference)
//
#include <hip/hip_runtime.h>
#include <math.h>
#include <stdint.h>

#define NTOK 131072
#define DIM  256
#define KEMB 1024

typedef _Float16 f16x8 __attribute__((ext_vector_type(8)));
typedef float    f32x4 __attribute__((ext_vector_type(4)));

#define FLAG_CAP 65536
#define FLAG_THR 8u    // prefix units (>=0.0625 each) -> flags any gap < ~0.5

static __device__ __forceinline__ unsigned umin32(unsigned a, unsigned b){ return a<b?a:b; }
static __device__ __forceinline__ unsigned umax32(unsigned a, unsigned b){ return a>b?a:b; }

static __device__ __forceinline__ void gload_lds16(const void* g, void* l) {
    __builtin_amdgcn_global_load_lds(
        (const __attribute__((address_space(1))) unsigned int*)g,
        (__attribute__((address_space(3))) unsigned int*)l, 16, 0, 0);
}

static __device__ __forceinline__ void split_hl(const float4& f0, const float4& f1,
                                                f16x8& h, f16x8& l) {
    float v[8] = {f0.x, f0.y, f0.z, f0.w, f1.x, f1.y, f1.z, f1.w};
    #pragma unroll
    for (int e = 0; e < 8; ++e) {
        const _Float16 hi = (_Float16)v[e];
        h[e] = hi;
        l[e] = (_Float16)(v[e] - (float)hi);
    }
}

// ---------------- prep: norms, cst2, counters, pre-swizzled hi/lo fp16 codebook ----
__global__ __launch_bounds__(64) void prep_kernel(const float* __restrict__ emb,
                                                  float* __restrict__ eNorm,
                                                  float* __restrict__ cst2,
                                                  unsigned* __restrict__ counts,
                                                  unsigned* __restrict__ flagCnt,
                                                  _Float16* __restrict__ img_hi,
                                                  _Float16* __restrict__ img_lo) {
    const int k = blockIdx.x;
    const int lane = threadIdx.x;
    const float4 v = *reinterpret_cast<const float4*>(emb + (size_t)k * DIM + lane * 4);
    float s = v.x * v.x + v.y * v.y + v.z * v.z + v.w * v.w;
    #pragma unroll
    for (int m = 32; m; m >>= 1) s += __shfl_xor(s, m, 64);
    if (lane == 0) {
        eNorm[k] = s;
        cst2[k]  = s + 512.0f;       // d = cst2 - 2*dot > 0 always
        counts[k] = 0u;
        if (k == 0) *flagCnt = 0u;
    }
    if (lane < 32) {
        const int p = lane;
        const int sl = p ^ (k & 7);
        const float4 f0 = *reinterpret_cast<const float4*>(emb + (size_t)k * DIM + sl * 8);
        const float4 f1 = *reinterpret_cast<const float4*>(emb + (size_t)k * DIM + sl * 8 + 4);
        f16x8 h, l;
        split_hl(f0, f1, h, l);
        *reinterpret_cast<f16x8*>(img_hi + (size_t)k * 256 + p * 8) = h;
        *reinterpret_cast<f16x8*>(img_lo + (size_t)k * 256 + p * 8) = l;
    }
}

// ---------------- main (templated for ablation) ----------------
// V=0: real kernel. V=1: no fold. V=2: stage+barrier skeleton only. V=3: no staging.
template<int V>
__global__ __launch_bounds__(256, 2) void vq_main(const float* __restrict__ x,
                                                  const float* __restrict__ emb,
                                                  const _Float16* __restrict__ img,
                                                  const float* __restrict__ cst2,
                                                  int* __restrict__ idxArr,
                                                  unsigned* __restrict__ counts,
                                                  unsigned* __restrict__ flagCnt,
                                                  unsigned* __restrict__ flagList,
                                                  float* __restrict__ out) {
    __shared__ _Float16 B[2][8192];    // 2 x 16KB chunk buffers (swizzled image, 32 rows)
    __shared__ float cst_s[1024];
    __shared__ int idx_s[128];

    const int tid  = threadIdx.x;
    const int wv   = tid >> 6;
    const int lane = tid & 63;
    const int g    = lane >> 4;
    const int c    = lane & 15;
    const int T0   = blockIdx.x * 128;
    const int T0w  = T0 + wv * 32;

    *reinterpret_cast<float4*>(&cst_s[tid * 4]) =
        *reinterpret_cast<const float4*>(&cst2[tid * 4]);

    // stage chunk 0
    #pragma unroll
    for (int i = 0; i < 4; ++i)
        gload_lds16((const char*)img + (i * 256 + tid) * 16,
                    (char*)&B[0][0] + i * 4096 + wv * 1024);

    // A fragments (not needed for V2 skeleton)
    f16x8 a[2][8];
    if constexpr (V != 2) {
        #pragma unroll
        for (int i = 0; i < 2; ++i) {
            const float* xr = x + (size_t)(T0w + i * 16 + c) * DIM + g * 8;
            #pragma unroll
            for (int kk = 0; kk < 8; ++kk) {
                const float4 f0 = *reinterpret_cast<const float4*>(xr + kk * 32);
                const float4 f1 = *reinterpret_cast<const float4*>(xr + kk * 32 + 4);
                a[i][kk] = (f16x8){(_Float16)f0.x, (_Float16)f0.y, (_Float16)f0.z, (_Float16)f0.w,
                                   (_Float16)f1.x, (_Float16)f1.y, (_Float16)f1.z, (_Float16)f1.w};
            }
        }
    }

    unsigned m1[8], m2[8];
    #pragma unroll
    for (int t = 0; t < 8; ++t) { m1[t] = 0xFFFFFFFFu; m2[t] = 0xFFFFFFFFu; }

    __syncthreads();

    for (int ec = 0; ec < 32; ++ec) {
        if constexpr (V != 3) {
            if (ec < 31) {
                const char* src = (const char*)img + (ec + 1) * 16384;
                char* dst = (char*)&B[(ec + 1) & 1][0];
                #pragma unroll
                for (int i = 0; i < 4; ++i)
                    gload_lds16(src + (i * 256 + tid) * 16, dst + i * 4096 + wv * 1024);
            }
        }

        if constexpr (V != 2) {
            const _Float16* Bc = (V == 3) ? &B[0][0] : &B[ec & 1][0];
            f32x4 acc[2][2];
            #pragma unroll
            for (int i = 0; i < 2; ++i)
                #pragma unroll
                for (int j = 0; j < 2; ++j) acc[i][j] = (f32x4){0.f, 0.f, 0.f, 0.f};

            #pragma unroll
            for (int kk = 0; kk < 8; ++kk) {
                f16x8 b[2];
                #pragma unroll
                for (int j = 0; j < 2; ++j) {
                    const int row = j * 16 + c;
                    const int s   = kk * 4 + g;
                    b[j] = *reinterpret_cast<const f16x8*>(&Bc[row * 256 + ((s ^ (row & 7)) << 3)]);
                }
                #pragma unroll
                for (int i = 0; i < 2; ++i)
                    #pragma unroll
                    for (int j = 0; j < 2; ++j)
                        acc[i][j] = __builtin_amdgcn_mfma_f32_16x16x32_f16(a[i][kk], b[j], acc[i][j], 0, 0, 0);
            }

            if constexpr (V == 1) {
                // keep MFMA results alive without folding (rule #17: anti-DCE)
                #pragma unroll
                for (int i = 0; i < 2; ++i)
                    #pragma unroll
                    for (int j = 0; j < 2; ++j)
                        asm volatile("" :: "v"(acc[i][j][0]), "v"(acc[i][j][1]),
                                           "v"(acc[i][j][2]), "v"(acc[i][j][3]));
            } else {
                // fold: key = (bits(d) & ~1023) | col
                #pragma unroll
                for (int j = 0; j < 2; ++j) {
                    const int   col = ec * 32 + j * 16 + c;
                    const float cst = cst_s[col];
                    #pragma unroll
                    for (int i = 0; i < 2; ++i)
                        #pragma unroll
                        for (int e = 0; e < 4; ++e) {
                            const float    d   = fmaf(acc[i][j][e], -2.0f, cst);
                            const unsigned key = (__builtin_bit_cast(unsigned, d) & 0xFFFFFC00u) | (unsigned)col;
                            const int t = i * 4 + e;
                            m2[t] = umin32(m2[t], umax32(key, m1[t]));
                            m1[t] = umin32(m1[t], key);
                        }
                }
            }
        }
        __syncthreads();
    }

    if constexpr (V != 0) {
        // keep running state alive; write nothing
        #pragma unroll
        for (int t = 0; t < 8; ++t)
            asm volatile("" :: "v"(m1[t]), "v"(m2[t]));
        return;
    }

    #pragma unroll
    for (int off = 1; off < 16; off <<= 1) {
        #pragma unroll
        for (int t = 0; t < 8; ++t) {
            const unsigned o1 = __shfl_xor(m1[t], off, 64);
            const unsigned o2 = __shfl_xor(m2[t], off, 64);
            const unsigned nm2 = umin32(umin32(m2[t], o2), umax32(m1[t], o1));
            m1[t] = umin32(m1[t], o1);
            m2[t] = nm2;
        }
    }

    if (c == 0) {
        #pragma unroll
        for (int t = 0; t < 8; ++t) {
            const int row = (t >> 2) * 16 + g * 4 + (t & 3);
            const int idx = (int)(m1[t] & 1023u);
            idx_s[wv * 32 + row] = idx;
            idxArr[T0w + row] = idx;
            atomicAdd(&counts[idx], 1u);
            if (((m2[t] >> 10) - (m1[t] >> 10)) < FLAG_THR) {
                const unsigned pos = atomicAdd(flagCnt, 1u);
                if (pos < FLAG_CAP) flagList[pos] = (unsigned)(T0w + row);
            }
        }
    }
    __syncthreads();

    // fused gather: out[token] = emb[idx]
    #pragma unroll 4
    for (int s = 0; s < 32; ++s) {
        const int fi  = s * 256 + tid;
        const int row = fi >> 6;
        const int q4  = fi & 63;
        const int em  = idx_s[row];
        *reinterpret_cast<float4*>(out + (size_t)(T0 + row) * DIM + q4 * 4) =
            *reinterpret_cast<const float4*>(emb + (size_t)em * DIM + q4 * 4);
    }
}

// ---------------- fixup stage A: hi/lo-split 3-MFMA full rescan -> refined top-2 ----
__global__ __launch_bounds__(256) void fixup_refine(const float* __restrict__ x,
                                                    const _Float16* __restrict__ img_hi,
                                                    const _Float16* __restrict__ img_lo,
                                                    const float* __restrict__ cst2,
                                                    const unsigned* __restrict__ flagCnt,
                                                    const unsigned* __restrict__ flagList,
                                                    uint2* __restrict__ refTop) {
    __shared__ _Float16 Bh[16384];
    __shared__ _Float16 Bl[16384];
    __shared__ float cst_s[1024];

    const unsigned nf = umin32(*flagCnt, (unsigned)FLAG_CAP);
    if (blockIdx.x * 64u >= nf) return;

    const int tid  = threadIdx.x;
    const int wv   = tid >> 6;
    const int lane = tid & 63;
    const int g    = lane >> 4;
    const int c    = lane & 15;
    const unsigned base = (blockIdx.x * 4u + (unsigned)wv) * 16u;

    *reinterpret_cast<float4*>(&cst_s[tid * 4]) =
        *reinterpret_cast<const float4*>(&cst2[tid * 4]);

    const unsigned myTok = flagList[(base + c) < nf ? (base + c) : 0];
    f16x8 ah[8], al[8];
    {
        const float* xr = x + (size_t)myTok * DIM + g * 8;
        #pragma unroll
        for (int kk = 0; kk < 8; ++kk) {
            const float4 f0 = *reinterpret_cast<const float4*>(xr + kk * 32);
            const float4 f1 = *reinterpret_cast<const float4*>(xr + kk * 32 + 4);
            split_hl(f0, f1, ah[kk], al[kk]);
        }
    }

    unsigned m1[4], m2[4];
    #pragma unroll
    for (int e = 0; e < 4; ++e) { m1[e] = 0xFFFFFFFFu; m2[e] = 0xFFFFFFFFu; }

    for (int ec = 0; ec < 16; ++ec) {
        __syncthreads();
        #pragma unroll
        for (int i = 0; i < 8; ++i) {
            gload_lds16((const char*)img_hi + ec * 32768 + (i * 256 + tid) * 16,
                        (char*)&Bh[0] + i * 4096 + wv * 1024);
            gload_lds16((const char*)img_lo + ec * 32768 + (i * 256 + tid) * 16,
                        (char*)&Bl[0] + i * 4096 + wv * 1024);
        }
        __syncthreads();

        f32x4 acc[4];
        #pragma unroll
        for (int j = 0; j < 4; ++j) acc[j] = (f32x4){0.f, 0.f, 0.f, 0.f};

        #pragma unroll
        for (int kk = 0; kk < 8; ++kk) {
            #pragma unroll
            for (int j = 0; j < 4; ++j) {
                const int row = j * 16 + c;
                const int off = row * 256 + (((kk * 4 + g) ^ (row & 7)) << 3);
                const f16x8 bh = *reinterpret_cast<const f16x8*>(&Bh[off]);
                const f16x8 bl = *reinterpret_cast<const f16x8*>(&Bl[off]);
                acc[j] = __builtin_amdgcn_mfma_f32_16x16x32_f16(ah[kk], bh, acc[j], 0, 0, 0);
                acc[j] = __builtin_amdgcn_mfma_f32_16x16x32_f16(ah[kk], bl, acc[j], 0, 0, 0);
                acc[j] = __builtin_amdgcn_mfma_f32_16x16x32_f16(al[kk], bh, acc[j], 0, 0, 0);
            }
        }

        #pragma unroll
        for (int j = 0; j < 4; ++j) {
            const int   col = ec * 64 + j * 16 + c;
            const float cst = cst_s[col];
            #pragma unroll
            for (int e = 0; e < 4; ++e) {
                const float    d   = fmaf(acc[j][e], -2.0f, cst);
                const unsigned key = (__builtin_bit_cast(unsigned, d) & 0xFFFFFC00u) | (unsigned)col;
                m2[e] = umin32(m2[e], umax32(key, m1[e]));
                m1[e] = umin32(m1[e], key);
            }
        }
    }

    #pragma unroll
    for (int off = 1; off < 16; off <<= 1) {
        #pragma unroll
        for (int e = 0; e < 4; ++e) {
            const unsigned o1 = __shfl_xor(m1[e], off, 64);
            const unsigned o2 = __shfl_xor(m2[e], off, 64);
            const unsigned nm2 = umin32(umin32(m2[e], o2), umax32(m1[e], o1));
            m1[e] = umin32(m1[e], o1);
            m2[e] = nm2;
        }
    }

    if (c == 0) {
        #pragma unroll
        for (int e = 0; e < 4; ++e) {
            const unsigned pos = base + (unsigned)(g * 4 + e);
            if (pos < nf) refTop[pos] = make_uint2(m1[e], m2[e]);
        }
    }
}

// ---------------- fixup stage B: exact fp32 compare of refined top-2, patch ----------
__global__ __launch_bounds__(256) void fixup_exact(const float* __restrict__ x,
                                                   const float* __restrict__ emb,
                                                   const float* __restrict__ eNorm,
                                                   const unsigned* __restrict__ flagCnt,
                                                   const unsigned* __restrict__ flagList,
                                                   const uint2* __restrict__ refTop,
                                                   int* __restrict__ idxArr,
                                                   unsigned* __restrict__ counts,
                                                   float* __restrict__ out) {
    const unsigned nf = umin32(*flagCnt, (unsigned)FLAG_CAP);
    const int tid  = threadIdx.x;
    const int wv   = tid >> 6;
    const int lane = tid & 63;

    for (unsigned pos = blockIdx.x * 4u + (unsigned)wv; pos < nf; pos += gridDim.x * 4u) {
        const unsigned tok = flagList[pos];
        const uint2 tk = refTop[pos];
        const int e1 = (int)(tk.x & 1023u);
        const int e2 = (int)(tk.y & 1023u);

        const float4 xv = *reinterpret_cast<const float4*>(x   + (size_t)tok * DIM + lane * 4);
        const float4 v1 = *reinterpret_cast<const float4*>(emb + (size_t)e1  * DIM + lane * 4);
        const float4 v2 = *reinterpret_cast<const float4*>(emb + (size_t)e2  * DIM + lane * 4);
        float p1 = xv.x * v1.x + xv.y * v1.y + xv.z * v1.z + xv.w * v1.w;
        float p2 = xv.x * v2.x + xv.y * v2.y + xv.z * v2.z + xv.w * v2.w;
        #pragma unroll
        for (int off = 1; off < 64; off <<= 1) {
            p1 += __shfl_xor(p1, off, 64);
            p2 += __shfl_xor(p2, off, 64);
        }
        const float d1 = eNorm[e1] - 2.0f * p1;
        const float d2 = eNorm[e2] - 2.0f * p2;
        const bool pick2 = (d2 < d1) || (d2 == d1 && e2 < e1);
        const int  ni   = pick2 ? e2 : e1;
        const int  old  = idxArr[tok];
        if (ni != old) {
            if (lane == 0) {
                idxArr[tok] = ni;
                atomicSub(&counts[old], 1u);
                atomicAdd(&counts[ni], 1u);
            }
            const float4 nv = pick2 ? v2 : v1;
            *reinterpret_cast<float4*>(out + (size_t)tok * DIM + lane * 4) = nv;
        }
    }
}

// ---------------- perplexity ----------------
__global__ __launch_bounds__(256) void perp_kernel(const unsigned* __restrict__ counts,
                                                   float* __restrict__ out_perp) {
    __shared__ float red[256];
    const int tid = threadIdx.x;
    float s = 0.0f;
    for (int i = tid; i < KEMB; i += 256) {
        const float p = (float)counts[i] / (float)NTOK;
        s += p * logf(p + 1e-10f);
    }
    red[tid] = s;
    __syncthreads();
    for (int off = 128; off; off >>= 1) {
        if (tid < off) red[tid] += red[tid + off];
        __syncthreads();
    }
    if (tid == 0) *out_perp = expf(-red[0]);
}

extern "C" void kernel_launch(void* const* d_in, const int* in_sizes, int n_in,
                              void* d_out, int out_size, void* d_ws, size_t ws_size,
                              hipStream_t stream) {
    (void)in_sizes; (void)n_in; (void)out_size; (void)ws_size;
    const float* x   = (const float*)d_in[0];
    const float* emb = (const float*)d_in[1];
    float* out = (float*)d_out;

    char* ws = (char*)d_ws;
    float*     eNorm    = (float*)(ws);                          // 4KB
    float*     cst2     = (float*)(ws + 4096);                   // 4KB
    unsigned*  counts   = (unsigned*)(ws + 8192);                // 4KB
    unsigned*  flagCnt  = (unsigned*)(ws + 12288);               // 4KB
    unsigned*  flagList = (unsigned*)(ws + 16384);               // 256KB
    int*       idxArr   = (int*)(ws + 278528);                   // 512KB
    _Float16*  img_hi   = (_Float16*)(ws + 802816);              // 512KB
    _Float16*  img_lo   = (_Float16*)(ws + 1327104);             // 512KB
    uint2*     refTop   = (uint2*)(ws + 1851392);                // 512KB

    prep_kernel<<<KEMB, 64, 0, stream>>>(emb, eNorm, cst2, counts, flagCnt, img_hi, img_lo);

    // ---- ablation probes (write nothing; diagnostic timing via rocprof) ----
    vq_main<1><<<NTOK / 128, 256, 0, stream>>>(x, emb, img_hi, cst2, idxArr, counts,
                                               flagCnt, flagList, out);
    vq_main<2><<<NTOK / 128, 256, 0, stream>>>(x, emb, img_hi, cst2, idxArr, counts,
                                               flagCnt, flagList, out);
    vq_main<3><<<NTOK / 128, 256, 0, stream>>>(x, emb, img_hi, cst2, idxArr, counts,
                                               flagCnt, flagList, out);

    // ---- real pipeline ----
    vq_main<0><<<NTOK / 128, 256, 0, stream>>>(x, emb, img_hi, cst2, idxArr, counts,
                                               flagCnt, flagList, out);
    fixup_refine<<<1024, 256, 0, stream>>>(x, img_hi, img_lo, cst2, flagCnt, flagList, refTop);
    fixup_exact<<<2048, 256, 0, stream>>>(x, emb, eNorm, flagCnt, flagList, refTop,
                                          idxArr, counts, out);
    perp_kernel<<<1, 256, 0, stream>>>(counts, out + (size_t)NTOK * DIM);
}

// Round 9
// 214.792 us; speedup vs baseline: 1.7534x; 1.7534x over previous
//
#include <hip/hip_runtime.h>
#include <math.h>
#include <stdint.h>

#define NTOK 131072
#define DIM  256
#define KEMB 1024

typedef _Float16 f16x8 __attribute__((ext_vector_type(8)));
typedef float    f32x4 __attribute__((ext_vector_type(4)));

#define FLAG_CAP 65536
#define FLAG_THR 8u    // prefix units (>=0.0625 each) -> flags any gap < ~0.5

static __device__ __forceinline__ unsigned umin32(unsigned a, unsigned b){ return a<b?a:b; }
static __device__ __forceinline__ unsigned umax32(unsigned a, unsigned b){ return a>b?a:b; }

static __device__ __forceinline__ void gload_lds16(const void* g, void* l) {
    __builtin_amdgcn_global_load_lds(
        (const __attribute__((address_space(1))) unsigned int*)g,
        (__attribute__((address_space(3))) unsigned int*)l, 16, 0, 0);
}

static __device__ __forceinline__ void split_hl(const float4& f0, const float4& f1,
                                                f16x8& h, f16x8& l) {
    float v[8] = {f0.x, f0.y, f0.z, f0.w, f1.x, f1.y, f1.z, f1.w};
    #pragma unroll
    for (int e = 0; e < 8; ++e) {
        const _Float16 hi = (_Float16)v[e];
        h[e] = hi;
        l[e] = (_Float16)(v[e] - (float)hi);
    }
}

// ---------------- prep: norms, cst2, counters, pre-swizzled hi/lo fp16 codebook ----
__global__ __launch_bounds__(64) void prep_kernel(const float* __restrict__ emb,
                                                  float* __restrict__ eNorm,
                                                  float* __restrict__ cst2,
                                                  unsigned* __restrict__ counts,
                                                  unsigned* __restrict__ flagCnt,
                                                  _Float16* __restrict__ img_hi,
                                                  _Float16* __restrict__ img_lo) {
    const int k = blockIdx.x;
    const int lane = threadIdx.x;
    const float4 v = *reinterpret_cast<const float4*>(emb + (size_t)k * DIM + lane * 4);
    float s = v.x * v.x + v.y * v.y + v.z * v.z + v.w * v.w;
    #pragma unroll
    for (int m = 32; m; m >>= 1) s += __shfl_xor(s, m, 64);
    if (lane == 0) {
        eNorm[k] = s;
        cst2[k]  = s + 512.0f;       // d = cst2 - 2*dot > 0 always
        counts[k] = 0u;
        if (k == 0) *flagCnt = 0u;
    }
    if (lane < 32) {
        const int p = lane;
        const int sl = p ^ (k & 7);
        const float4 f0 = *reinterpret_cast<const float4*>(emb + (size_t)k * DIM + sl * 8);
        const float4 f1 = *reinterpret_cast<const float4*>(emb + (size_t)k * DIM + sl * 8 + 4);
        f16x8 h, l;
        split_hl(f0, f1, h, l);
        *reinterpret_cast<f16x8*>(img_hi + (size_t)k * 256 + p * 8) = h;
        *reinterpret_cast<f16x8*>(img_lo + (size_t)k * 256 + p * 8) = l;
    }
}

// ---------------- main: fp16 MFMA + packed-key top2 + fused gather/hist ----------------
__global__ __launch_bounds__(256, 2) void vq_main(const float* __restrict__ x,
                                                  const float* __restrict__ emb,
                                                  const _Float16* __restrict__ img,
                                                  const float* __restrict__ cst2,
                                                  int* __restrict__ idxArr,
                                                  unsigned* __restrict__ counts,
                                                  unsigned* __restrict__ flagCnt,
                                                  unsigned* __restrict__ flagList,
                                                  float* __restrict__ out) {
    __shared__ _Float16 B[2][8192];    // 2 x 16KB chunk buffers (swizzled image, 32 rows)
    __shared__ float cst_s[1024];
    __shared__ int idx_s[128];

    const int tid  = threadIdx.x;
    const int wv   = tid >> 6;
    const int lane = tid & 63;
    const int g    = lane >> 4;
    const int c    = lane & 15;
    const int T0   = blockIdx.x * 128;
    const int T0w  = T0 + wv * 32;

    *reinterpret_cast<float4*>(&cst_s[tid * 4]) =
        *reinterpret_cast<const float4*>(&cst2[tid * 4]);

    // stage chunk 0
    #pragma unroll
    for (int i = 0; i < 4; ++i)
        gload_lds16((const char*)img + (i * 256 + tid) * 16,
                    (char*)&B[0][0] + i * 4096 + wv * 1024);

    // A fragments: x[token][k], token = T0w + i*16 + c, k = kk*32 + g*8 ..
    f16x8 a[2][8];
    #pragma unroll
    for (int i = 0; i < 2; ++i) {
        const float* xr = x + (size_t)(T0w + i * 16 + c) * DIM + g * 8;
        #pragma unroll
        for (int kk = 0; kk < 8; ++kk) {
            const float4 f0 = *reinterpret_cast<const float4*>(xr + kk * 32);
            const float4 f1 = *reinterpret_cast<const float4*>(xr + kk * 32 + 4);
            a[i][kk] = (f16x8){(_Float16)f0.x, (_Float16)f0.y, (_Float16)f0.z, (_Float16)f0.w,
                               (_Float16)f1.x, (_Float16)f1.y, (_Float16)f1.z, (_Float16)f1.w};
        }
    }
    // PIN the A fragments: values become asm-opaque so the register allocator
    // cannot rematerialize them by re-reading x inside the loop (R8 diagnosis:
    // VGPR_Count=76 < 64 needed for A => compiler was re-loading x every chunk,
    // ~4.3 GB of L2 traffic). This forces 64 VGPRs to stay live across the loop.
    #pragma unroll
    for (int i = 0; i < 2; ++i)
        #pragma unroll
        for (int kk = 0; kk < 8; ++kk)
            asm volatile("" : "+v"(a[i][kk]));

    unsigned m1[8], m2[8];
    #pragma unroll
    for (int t = 0; t < 8; ++t) { m1[t] = 0xFFFFFFFFu; m2[t] = 0xFFFFFFFFu; }

    __syncthreads();

    for (int ec = 0; ec < 32; ++ec) {
        if (ec < 31) {
            const char* src = (const char*)img + (ec + 1) * 16384;
            char* dst = (char*)&B[(ec + 1) & 1][0];
            #pragma unroll
            for (int i = 0; i < 4; ++i)
                gload_lds16(src + (i * 256 + tid) * 16, dst + i * 4096 + wv * 1024);
        }

        const _Float16* Bc = &B[ec & 1][0];
        f32x4 acc[2][2];
        #pragma unroll
        for (int i = 0; i < 2; ++i)
            #pragma unroll
            for (int j = 0; j < 2; ++j) acc[i][j] = (f32x4){0.f, 0.f, 0.f, 0.f};

        #pragma unroll
        for (int kk = 0; kk < 8; ++kk) {
            f16x8 b[2];
            #pragma unroll
            for (int j = 0; j < 2; ++j) {
                const int row = j * 16 + c;
                const int s   = kk * 4 + g;
                b[j] = *reinterpret_cast<const f16x8*>(&Bc[row * 256 + ((s ^ (row & 7)) << 3)]);
            }
            #pragma unroll
            for (int i = 0; i < 2; ++i)
                #pragma unroll
                for (int j = 0; j < 2; ++j)
                    acc[i][j] = __builtin_amdgcn_mfma_f32_16x16x32_f16(a[i][kk], b[j], acc[i][j], 0, 0, 0);
        }

        // fold: key = (bits(d) & ~1023) | col  (d > 0 -> bits monotone in d)
        #pragma unroll
        for (int j = 0; j < 2; ++j) {
            const int   col = ec * 32 + j * 16 + c;
            const float cst = cst_s[col];
            #pragma unroll
            for (int i = 0; i < 2; ++i)
                #pragma unroll
                for (int e = 0; e < 4; ++e) {
                    const float    d   = fmaf(acc[i][j][e], -2.0f, cst);
                    const unsigned key = (__builtin_bit_cast(unsigned, d) & 0xFFFFFC00u) | (unsigned)col;
                    const int t = i * 4 + e;
                    m2[t] = umin32(m2[t], umax32(key, m1[t]));
                    m1[t] = umin32(m1[t], key);
                }
        }
        __syncthreads();
    }

    #pragma unroll
    for (int off = 1; off < 16; off <<= 1) {
        #pragma unroll
        for (int t = 0; t < 8; ++t) {
            const unsigned o1 = __shfl_xor(m1[t], off, 64);
            const unsigned o2 = __shfl_xor(m2[t], off, 64);
            const unsigned nm2 = umin32(umin32(m2[t], o2), umax32(m1[t], o1));
            m1[t] = umin32(m1[t], o1);
            m2[t] = nm2;
        }
    }

    if (c == 0) {
        #pragma unroll
        for (int t = 0; t < 8; ++t) {
            const int row = (t >> 2) * 16 + g * 4 + (t & 3);
            const int idx = (int)(m1[t] & 1023u);
            idx_s[wv * 32 + row] = idx;
            idxArr[T0w + row] = idx;
            atomicAdd(&counts[idx], 1u);
            if (((m2[t] >> 10) - (m1[t] >> 10)) < FLAG_THR) {
                const unsigned pos = atomicAdd(flagCnt, 1u);
                if (pos < FLAG_CAP) flagList[pos] = (unsigned)(T0w + row);
            }
        }
    }
    __syncthreads();

    // fused gather: out[token] = emb[idx]
    #pragma unroll 4
    for (int s = 0; s < 32; ++s) {
        const int fi  = s * 256 + tid;
        const int row = fi >> 6;
        const int q4  = fi & 63;
        const int em  = idx_s[row];
        *reinterpret_cast<float4*>(out + (size_t)(T0 + row) * DIM + q4 * 4) =
            *reinterpret_cast<const float4*>(emb + (size_t)em * DIM + q4 * 4);
    }
}

// ---------------- fixup stage A: hi/lo-split 3-MFMA full rescan -> refined top-2 ----
__global__ __launch_bounds__(256) void fixup_refine(const float* __restrict__ x,
                                                    const _Float16* __restrict__ img_hi,
                                                    const _Float16* __restrict__ img_lo,
                                                    const float* __restrict__ cst2,
                                                    const unsigned* __restrict__ flagCnt,
                                                    const unsigned* __restrict__ flagList,
                                                    uint2* __restrict__ refTop) {
    __shared__ _Float16 Bh[16384];
    __shared__ _Float16 Bl[16384];
    __shared__ float cst_s[1024];

    const unsigned nf = umin32(*flagCnt, (unsigned)FLAG_CAP);
    if (blockIdx.x * 64u >= nf) return;

    const int tid  = threadIdx.x;
    const int wv   = tid >> 6;
    const int lane = tid & 63;
    const int g    = lane >> 4;
    const int c    = lane & 15;
    const unsigned base = (blockIdx.x * 4u + (unsigned)wv) * 16u;

    *reinterpret_cast<float4*>(&cst_s[tid * 4]) =
        *reinterpret_cast<const float4*>(&cst2[tid * 4]);

    const unsigned myTok = flagList[(base + c) < nf ? (base + c) : 0];
    f16x8 ah[8], al[8];
    {
        const float* xr = x + (size_t)myTok * DIM + g * 8;
        #pragma unroll
        for (int kk = 0; kk < 8; ++kk) {
            const float4 f0 = *reinterpret_cast<const float4*>(xr + kk * 32);
            const float4 f1 = *reinterpret_cast<const float4*>(xr + kk * 32 + 4);
            split_hl(f0, f1, ah[kk], al[kk]);
        }
    }

    unsigned m1[4], m2[4];
    #pragma unroll
    for (int e = 0; e < 4; ++e) { m1[e] = 0xFFFFFFFFu; m2[e] = 0xFFFFFFFFu; }

    for (int ec = 0; ec < 16; ++ec) {
        __syncthreads();
        #pragma unroll
        for (int i = 0; i < 8; ++i) {
            gload_lds16((const char*)img_hi + ec * 32768 + (i * 256 + tid) * 16,
                        (char*)&Bh[0] + i * 4096 + wv * 1024);
            gload_lds16((const char*)img_lo + ec * 32768 + (i * 256 + tid) * 16,
                        (char*)&Bl[0] + i * 4096 + wv * 1024);
        }
        __syncthreads();

        f32x4 acc[4];
        #pragma unroll
        for (int j = 0; j < 4; ++j) acc[j] = (f32x4){0.f, 0.f, 0.f, 0.f};

        #pragma unroll
        for (int kk = 0; kk < 8; ++kk) {
            #pragma unroll
            for (int j = 0; j < 4; ++j) {
                const int row = j * 16 + c;
                const int off = row * 256 + (((kk * 4 + g) ^ (row & 7)) << 3);
                const f16x8 bh = *reinterpret_cast<const f16x8*>(&Bh[off]);
                const f16x8 bl = *reinterpret_cast<const f16x8*>(&Bl[off]);
                acc[j] = __builtin_amdgcn_mfma_f32_16x16x32_f16(ah[kk], bh, acc[j], 0, 0, 0);
                acc[j] = __builtin_amdgcn_mfma_f32_16x16x32_f16(ah[kk], bl, acc[j], 0, 0, 0);
                acc[j] = __builtin_amdgcn_mfma_f32_16x16x32_f16(al[kk], bh, acc[j], 0, 0, 0);
            }
        }

        #pragma unroll
        for (int j = 0; j < 4; ++j) {
            const int   col = ec * 64 + j * 16 + c;
            const float cst = cst_s[col];
            #pragma unroll
            for (int e = 0; e < 4; ++e) {
                const float    d   = fmaf(acc[j][e], -2.0f, cst);
                const unsigned key = (__builtin_bit_cast(unsigned, d) & 0xFFFFFC00u) | (unsigned)col;
                m2[e] = umin32(m2[e], umax32(key, m1[e]));
                m1[e] = umin32(m1[e], key);
            }
        }
    }

    #pragma unroll
    for (int off = 1; off < 16; off <<= 1) {
        #pragma unroll
        for (int e = 0; e < 4; ++e) {
            const unsigned o1 = __shfl_xor(m1[e], off, 64);
            const unsigned o2 = __shfl_xor(m2[e], off, 64);
            const unsigned nm2 = umin32(umin32(m2[e], o2), umax32(m1[e], o1));
            m1[e] = umin32(m1[e], o1);
            m2[e] = nm2;
        }
    }

    if (c == 0) {
        #pragma unroll
        for (int e = 0; e < 4; ++e) {
            const unsigned pos = base + (unsigned)(g * 4 + e);
            if (pos < nf) refTop[pos] = make_uint2(m1[e], m2[e]);
        }
    }
}

// ---------------- fixup stage B: exact fp32 compare of refined top-2, patch ----------
__global__ __launch_bounds__(256) void fixup_exact(const float* __restrict__ x,
                                                   const float* __restrict__ emb,
                                                   const float* __restrict__ eNorm,
                                                   const unsigned* __restrict__ flagCnt,
                                                   const unsigned* __restrict__ flagList,
                                                   const uint2* __restrict__ refTop,
                                                   int* __restrict__ idxArr,
                                                   unsigned* __restrict__ counts,
                                                   float* __restrict__ out) {
    const unsigned nf = umin32(*flagCnt, (unsigned)FLAG_CAP);
    const int tid  = threadIdx.x;
    const int wv   = tid >> 6;
    const int lane = tid & 63;

    for (unsigned pos = blockIdx.x * 4u + (unsigned)wv; pos < nf; pos += gridDim.x * 4u) {
        const unsigned tok = flagList[pos];
        const uint2 tk = refTop[pos];
        const int e1 = (int)(tk.x & 1023u);
        const int e2 = (int)(tk.y & 1023u);

        const float4 xv = *reinterpret_cast<const float4*>(x   + (size_t)tok * DIM + lane * 4);
        const float4 v1 = *reinterpret_cast<const float4*>(emb + (size_t)e1  * DIM + lane * 4);
        const float4 v2 = *reinterpret_cast<const float4*>(emb + (size_t)e2  * DIM + lane * 4);
        float p1 = xv.x * v1.x + xv.y * v1.y + xv.z * v1.z + xv.w * v1.w;
        float p2 = xv.x * v2.x + xv.y * v2.y + xv.z * v2.z + xv.w * v2.w;
        #pragma unroll
        for (int off = 1; off < 64; off <<= 1) {
            p1 += __shfl_xor(p1, off, 64);
            p2 += __shfl_xor(p2, off, 64);
        }
        const float d1 = eNorm[e1] - 2.0f * p1;
        const float d2 = eNorm[e2] - 2.0f * p2;
        const bool pick2 = (d2 < d1) || (d2 == d1 && e2 < e1);
        const int  ni   = pick2 ? e2 : e1;
        const int  old  = idxArr[tok];
        if (ni != old) {
            if (lane == 0) {
                idxArr[tok] = ni;
                atomicSub(&counts[old], 1u);
                atomicAdd(&counts[ni], 1u);
            }
            const float4 nv = pick2 ? v2 : v1;
            *reinterpret_cast<float4*>(out + (size_t)tok * DIM + lane * 4) = nv;
        }
    }
}

// ---------------- perplexity ----------------
__global__ __launch_bounds__(256) void perp_kernel(const unsigned* __restrict__ counts,
                                                   float* __restrict__ out_perp) {
    __shared__ float red[256];
    const int tid = threadIdx.x;
    float s = 0.0f;
    for (int i = tid; i < KEMB; i += 256) {
        const float p = (float)counts[i] / (float)NTOK;
        s += p * logf(p + 1e-10f);
    }
    red[tid] = s;
    __syncthreads();
    for (int off = 128; off; off >>= 1) {
        if (tid < off) red[tid] += red[tid + off];
        __syncthreads();
    }
    if (tid == 0) *out_perp = expf(-red[0]);
}

extern "C" void kernel_launch(void* const* d_in, const int* in_sizes, int n_in,
                              void* d_out, int out_size, void* d_ws, size_t ws_size,
                              hipStream_t stream) {
    (void)in_sizes; (void)n_in; (void)out_size; (void)ws_size;
    const float* x   = (const float*)d_in[0];
    const float* emb = (const float*)d_in[1];
    float* out = (float*)d_out;

    char* ws = (char*)d_ws;
    float*     eNorm    = (float*)(ws);                          // 4KB
    float*     cst2     = (float*)(ws + 4096);                   // 4KB
    unsigned*  counts   = (unsigned*)(ws + 8192);                // 4KB
    unsigned*  flagCnt  = (unsigned*)(ws + 12288);               // 4KB
    unsigned*  flagList = (unsigned*)(ws + 16384);               // 256KB
    int*       idxArr   = (int*)(ws + 278528);                   // 512KB
    _Float16*  img_hi   = (_Float16*)(ws + 802816);              // 512KB
    _Float16*  img_lo   = (_Float16*)(ws + 1327104);             // 512KB
    uint2*     refTop   = (uint2*)(ws + 1851392);                // 512KB

    prep_kernel<<<KEMB, 64, 0, stream>>>(emb, eNorm, cst2, counts, flagCnt, img_hi, img_lo);
    vq_main<<<NTOK / 128, 256, 0, stream>>>(x, emb, img_hi, cst2, idxArr, counts,
                                            flagCnt, flagList, out);
    fixup_refine<<<1024, 256, 0, stream>>>(x, img_hi, img_lo, cst2, flagCnt, flagList, refTop);
    fixup_exact<<<2048, 256, 0, stream>>>(x, emb, eNorm, flagCnt, flagList, refTop,
                                          idxArr, counts, out);
    perp_kernel<<<1, 256, 0, stream>>>(counts, out + (size_t)NTOK * DIM);
}